// Round 11
// baseline (175.913 us; speedup 1.0000x reference)
//
#include <hip/hip_runtime.h>
#include <hip/hip_bf16.h>

// MPNScoreModule: B=8 graphs, N=64 nodes, E=256 edges, L=128, S=2 steps.
// Round 21: round-19 (16-wave main) with __launch_bounds__(1024, 4).
// r20 post-mortem: the separate amdgpu_waves_per_eu(4,4) attribute was
// IGNORED (VGPR stayed 64, spill traffic unchanged) -- HIP's
// __launch_bounds__(1024,1) already emits amdgpu-waves-per-eu with min=1
// and the duplicate attribute was dropped. The second launch_bounds arg
// IS min-waves-per-EU on HIP: (1024, 4) -> min 4 waves/EU -> VGPR budget
// 512/4 = 128 -> the ~128-VGPR weight prefetch fits spill-free, and
// k = 4*4/(1024/64) = 1 block/CU (the LDS-forced residency anyway).
// r19/r20 ran 68us moving ~98MB scratch at 1.43TB/s == scratch-BW-bound;
// removing the spill at 40% occupancy is the whole bet.

typedef __attribute__((ext_vector_type(8))) __bf16 bf16x8;
typedef __attribute__((ext_vector_type(4))) __bf16 bf16x4;
typedef __attribute__((ext_vector_type(4))) float  floatx4;

#define MFMA16(a, b, c) __builtin_amdgcn_mfma_f32_16x16x32_bf16((a), (b), (c), 0, 0, 0)

__device__ __forceinline__ float leaky(float x) { return x > 0.f ? x : 0.01f * x; }

// ---- workspace layout (bytes) ----
#define WS_WT     0          // bf16 [10][16384] PACKED weights: [m][(mq*4+c)*64+l][8]
#define WS_XAP    327680     // f32  [8][64][128]  x @ Wne[0:128] + b_node_enc
#define WS_XDP    589824     // f32  [8][64][128]  x @ Wne[128:256]
#define WS_EE0    851968     // bf16 [8][256][128] leaky(edge_attr @ Wee + b)
#define WS_CE     1376256    // f32  [8][2][128]   gg @ W4  + b_edge_upd
#define WS_CN     1384448    // f32  [8][2][128]   gg @ Wn3 + b_node_upd
#define WS_CSROFF 1392640    // int  [8][72]
#define WS_CSREID 1394944    // int  [8][256]
// end ~1.4 MB

#define LDE 140   // padded LDS row stride: 280 B = 70 dw = 6 mod 32 -> conflict-free

// ============================ prep kernel (round 8, unchanged) ============================
__global__ __launch_bounds__(256) void mpn_prep(
    const float* __restrict__ x,     // [8][64][128]
    const float* __restrict__ ea,    // [8][256][128]
    const float* __restrict__ u,     // [8][128]
    const int*   __restrict__ eidx,  // [8][2][256]
    const float* __restrict__ Wne,   // [257][128]
    const float* __restrict__ bne,   // [128]
    const float* __restrict__ Wee,   // [128][128]
    const float* __restrict__ bee,   // [128]
    const float* __restrict__ Wge,   // [128][128]
    const float* __restrict__ bge,   // [128]
    const float* __restrict__ Weu,   // [2][512][128]
    const float* __restrict__ beu,   // [2][128]
    const float* __restrict__ Wnu,   // [2][384][128]
    const float* __restrict__ bnu,   // [2][128]
    char* __restrict__ ws)
{
  __shared__ __align__(16) __bf16 smem[384 * LDE];

  const int b = blockIdx.x, tid = threadIdx.x;
  __bf16* wt  = (__bf16*)(ws + WS_WT);
  float*  xap = (float*)(ws + WS_XAP);
  float*  xdp = (float*)(ws + WS_XDP);
  __bf16* ee0 = (__bf16*)(ws + WS_EE0);
  float*  cev = (float*)(ws + WS_CE);
  float*  cnv = (float*)(ws + WS_CN);
  int* csroff = (int*)(ws + WS_CSROFF);
  int* csreid = (int*)(ws + WS_CSREID);

  if (b < 20) {
    // pack the 10 [128][128] weight blocks into wave-load order:
    // wt[m*16384 + ((mq*4+c)*64 + l)*8 + j] = src[(c*32 + (l>>4)*8 + j)*128 + mq*16 + (l&15)]
    const int m = b >> 1, half = b & 1;
    const int s = m / 5, t = m % 5;
    const float* src = (t < 3) ? (Weu + (size_t)(s*512 + t*128)*128)
                               : (Wnu + (size_t)(s*384 + (t-3)*128)*128);
    for (int it = 0; it < 4; ++it) {
      int p = it*256 + tid;
      int mq = half*4 + (p >> 8);
      int c  = (p >> 6) & 3;
      int l  = p & 63;
      int fr = mq*16 + (l & 15);
      int kb = c*32 + (l >> 4)*8;
      __bf16* dst = &wt[m*16384 + ((mq*4 + c)*64 + l)*8];
      #pragma unroll
      for (int j = 0; j < 8; ++j)
        dst[j] = (__bf16)src[(kb + j)*128 + fr];
    }
  } else if (b < 28) {
    const int g = b - 20;
    __shared__ float gg_sh[128];
    __shared__ int dst_sh[256];
    __shared__ int cnt_sh[64];
    __shared__ int off_sh[65];
    if (tid < 128) {
      float acc = bge[tid];
      for (int k = 0; k < 128; ++k)
        acc += u[g*128 + k] * Wge[k*128 + tid];
      gg_sh[tid] = leaky(acc);
    }
    dst_sh[tid] = eidx[g*512 + 256 + tid];
    __syncthreads();
    {
      const int s = tid >> 7, f = tid & 127;
      float ac = beu[s*128 + f];
      float an = bnu[s*128 + f];
      #pragma unroll 8
      for (int k = 0; k < 128; ++k) {
        float gk = gg_sh[k];
        ac += gk * Weu[(s*512 + 384 + k)*128 + f];
        an += gk * Wnu[(s*384 + 256 + k)*128 + f];
      }
      cev[(g*2 + s)*128 + f] = ac;
      cnv[(g*2 + s)*128 + f] = an;
    }
    if (tid < 64) {
      int c = 0;
      for (int e = 0; e < 256; ++e) c += (dst_sh[e] == tid) ? 1 : 0;
      cnt_sh[tid] = c;
    }
    __syncthreads();
    if (tid == 0) {
      int o = 0;
      for (int n = 0; n < 64; ++n) { off_sh[n] = o; o += cnt_sh[n]; }
      off_sh[64] = o;
    }
    __syncthreads();
    if (tid < 65) csroff[g*72 + tid] = off_sh[tid];
    if (tid < 64) {
      int o = off_sh[tid];
      for (int e = 0; e < 256; ++e)
        if (dst_sh[e] == tid) csreid[g*256 + (o++)] = e;
    }
  } else if (b < 36) {
    // ee0 = leaky(edge_attr @ Wee + bee) via MFMA, one block per graph
    const int g = b - 28;
    __bf16* s_a = smem;
    __bf16* s_w = smem + 256*LDE;
    #pragma unroll
    for (int it = 0; it < 32; ++it) {
      int c = it*256 + tid;
      int row = c >> 5, f4 = (c & 31)*4;
      floatx4 v = *(const floatx4*)&ea[(size_t)(g*256 + row)*128 + f4];
      bf16x4 o;
      #pragma unroll
      for (int r = 0; r < 4; ++r) o[r] = (__bf16)v[r];
      *(bf16x4*)&s_a[row*LDE + f4] = o;
    }
    #pragma unroll 8
    for (int it = 0; it < 64; ++it) {
      int k = it*2 + (tid >> 7), f = tid & 127;
      s_w[f*LDE + k] = (__bf16)Wee[k*128 + f];
    }
    __syncthreads();
    const int w = tid >> 6, l = tid & 63, q = l >> 4, xn = l & 15;
    bf16x8 bea[4][4];
    #pragma unroll
    for (int t = 0; t < 4; ++t) {
      int e = w*64 + t*16 + xn;
      #pragma unroll
      for (int c = 0; c < 4; ++c)
        bea[t][c] = *(const bf16x8*)&s_a[e*LDE + c*32 + q*8];
    }
    #pragma unroll
    for (int m = 0; m < 8; ++m) {
      floatx4 acc[4];
      #pragma unroll
      for (int t = 0; t < 4; ++t) acc[t] = (floatx4)0.f;
      const int fr = m*16 + xn;
      #pragma unroll
      for (int c = 0; c < 4; ++c) {
        bf16x8 aw = *(const bf16x8*)&s_w[fr*LDE + c*32 + q*8];
        #pragma unroll
        for (int t = 0; t < 4; ++t) acc[t] = MFMA16(aw, bea[t][c], acc[t]);
      }
      const int f0 = m*16 + q*4;
      floatx4 b4 = *(const floatx4*)&bee[f0];
      #pragma unroll
      for (int t = 0; t < 4; ++t) {
        int e = w*64 + t*16 + xn;
        bf16x4 o;
        #pragma unroll
        for (int r = 0; r < 4; ++r) o[r] = (__bf16)leaky(acc[t][r] + b4[r]);
        *(bf16x4*)&ee0[(size_t)(g*256 + e)*128 + f0] = o;
      }
    }
  } else {
    // xap = x @ Wne[0:128] + bne ; xdp = x @ Wne[128:256]  via MFMA, per graph
    const int g = b - 36;
    __bf16* s_x  = smem;
    __bf16* s_wa = smem + 64*LDE;
    __bf16* s_wb = smem + 192*LDE;
    #pragma unroll
    for (int it = 0; it < 8; ++it) {
      int c = it*256 + tid;
      int row = c >> 5, f4 = (c & 31)*4;
      floatx4 v = *(const floatx4*)&x[(size_t)(g*64 + row)*128 + f4];
      bf16x4 o;
      #pragma unroll
      for (int r = 0; r < 4; ++r) o[r] = (__bf16)v[r];
      *(bf16x4*)&s_x[row*LDE + f4] = o;
    }
    #pragma unroll 8
    for (int it = 0; it < 64; ++it) {
      int k = it*2 + (tid >> 7), f = tid & 127;
      s_wa[f*LDE + k] = (__bf16)Wne[k*128 + f];
      s_wb[f*LDE + k] = (__bf16)Wne[(128 + k)*128 + f];
    }
    __syncthreads();
    const int w = tid >> 6, l = tid & 63, q = l >> 4, xn = l & 15;
    const int i = w*16 + xn;
    bf16x8 bx[4];
    #pragma unroll
    for (int c = 0; c < 4; ++c)
      bx[c] = *(const bf16x8*)&s_x[i*LDE + c*32 + q*8];
    #pragma unroll
    for (int m = 0; m < 8; ++m) {
      floatx4 aa = (floatx4)0.f, ab = (floatx4)0.f;
      const int fr = m*16 + xn;
      #pragma unroll
      for (int c = 0; c < 4; ++c) {
        bf16x8 aw = *(const bf16x8*)&s_wa[fr*LDE + c*32 + q*8];
        aa = MFMA16(aw, bx[c], aa);
      }
      #pragma unroll
      for (int c = 0; c < 4; ++c) {
        bf16x8 aw = *(const bf16x8*)&s_wb[fr*LDE + c*32 + q*8];
        ab = MFMA16(aw, bx[c], ab);
      }
      const int f0 = m*16 + q*4;
      floatx4 bn4 = *(const floatx4*)&bne[f0];
      floatx4 oa;
      #pragma unroll
      for (int r = 0; r < 4; ++r) oa[r] = aa[r] + bn4[r];
      *(floatx4*)&xap[(size_t)(g*64 + i)*128 + f0] = oa;
      *(floatx4*)&xdp[(size_t)(g*64 + i)*128 + f0] = ab;
    }
  }
}

// ============================ main kernel ============================
// 1024 threads = 16 waves, __launch_bounds__(1024, 4): min 4 waves/EU ->
// VGPR budget 512/4 = 128 (fits the weight prefetch spill-free), and
// 4 waves/EU * 4 EU / 16 waves = 1 block/CU (the LDS-forced residency).
// Phases 1/4: wave w -> (m = w>>1, node-half nh = w&1), t in [0,2).
// Phase 2: 8 wave-pairs x 32 edges, mh = w&1 splits m; be[2][4], acc[2].
// Phase 3: 16 thr/node x 8 features. Scores: 4 thr/edge + shfl_xor.
__global__ __launch_bounds__(1024, 4)
void mpn_main(
    const float* __restrict__ spdist,  // [8][64][64]
    const int*   __restrict__ eidx,    // [8][2][256]
    const float* __restrict__ Wne,     // row 256 = spdist weight
    const float* __restrict__ wscore,  // [128]
    const float* __restrict__ bscore,  // [1]
    const char* __restrict__ ws,
    float* __restrict__ out)           // [8][256][64]  (g*16384 + e*64 + d), fp32
{
  __shared__ __align__(16) __bf16 s_ee[256*LDE];   // edge state
  __shared__ __align__(16) __bf16 s_h [64*LDE];    // node state
  __shared__ __align__(16) __bf16 s_p2[64*LDE];    // h@W2 (reused as agg)
  __shared__ __align__(16) __bf16 s_p3[64*LDE];    // h@W3 + ce
  __shared__ int s_off[65];
  __shared__ int s_eid[256];

  const __bf16* wt  = (const __bf16*)(ws + WS_WT);
  const float*  xap = (const float*)(ws + WS_XAP);
  const float*  xdp = (const float*)(ws + WS_XDP);
  const __bf16* ee0 = (const __bf16*)(ws + WS_EE0);
  const float*  cev = (const float*)(ws + WS_CE);
  const float*  cnv = (const float*)(ws + WS_CN);
  const int* csroff = (const int*)(ws + WS_CSROFF);
  const int* csreid = (const int*)(ws + WS_CSREID);

  const int tid = threadIdx.x;
  const int w = tid >> 6, l = tid & 63;
  const int q = l >> 4, xn = l & 15;
  const int wp = w >> 1;                  // phase-2 wave pair (8 pairs x 32 edges)
  const int mh = w & 1;                   // phase-2 m-half
  const int m8 = w >> 1;                  // phase-1/4 m-slice in [0,8)
  const int nh = w & 1;                   // phase-1/4 node-half
  const int lane8 = l*8;                  // packed-fragment lane offset
  const int fme = m8*16 + q*4;            // phase-1/4 epilogue f-offset
  const int g = blockIdx.x >> 6, d = blockIdx.x & 63;

  if (tid < 65) s_off[tid] = csroff[g*72 + tid];
  if (tid < 256) s_eid[tid] = csreid[g*256 + tid];

  // node encoder: h[i][f] = leaky(xap[i][f] + xdp[d][f] + sp(d,i)*wsp[f])
  {
    const int f = tid & 127, ib = tid >> 7;   // ib in [0,8)
    float xdpv = xdp[(g*64 + d)*128 + f];
    float wspv = Wne[256*128 + f];
    #pragma unroll
    for (int j = 0; j < 8; ++j) {
      int i = ib + 8*j;
      float sp = spdist[(g*64 + d)*64 + i];
      float v = xap[(g*64 + i)*128 + f] + xdpv + sp*wspv;
      s_h[i*LDE + f] = (__bf16)leaky(v);
    }
  }
  // stage ee0 -> LDS (4096 chunks of 16B)
  #pragma unroll
  for (int it = 0; it < 4; ++it) {
    int c = it*1024 + tid;
    int row = c >> 4, col = c & 15;
    *(bf16x8*)&s_ee[row*LDE + col*8] = *(const bf16x8*)&ee0[(g*256 + row)*128 + col*8];
  }

  // phase-2 per-lane src/dst (e = wp*32 + t*16 + xn)
  int mySrc[2], myDst[2];
  #pragma unroll
  for (int t = 0; t < 2; ++t) {
    int e = wp*32 + t*16 + xn;
    mySrc[t] = eidx[g*512 + e];
    myDst[t] = eidx[g*512 + 256 + e];
  }
  __syncthreads();

  for (int s = 0; s < 2; ++s) {
    const __bf16* W1T = wt + (s*5 + 0)*16384;
    const __bf16* W2T = wt + (s*5 + 1)*16384;
    const __bf16* W3T = wt + (s*5 + 2)*16384;
    const __bf16* N1T = wt + (s*5 + 3)*16384;
    const __bf16* N2T = wt + (s*5 + 4)*16384;

    // ---- step-start weight prefetch (all L2 loads issued before any compute)
    bf16x8 w2f[4], w3f[4], n1f[4], n2f[4], w1f[4][4];
    #pragma unroll
    for (int c = 0; c < 4; ++c) {
      w2f[c] = *(const bf16x8*)&W2T[(m8*4 + c)*512 + lane8];
      w3f[c] = *(const bf16x8*)&W3T[(m8*4 + c)*512 + lane8];
    }
    #pragma unroll
    for (int mm = 0; mm < 4; ++mm)
      #pragma unroll
      for (int c = 0; c < 4; ++c)
        w1f[mm][c] = *(const bf16x8*)&W1T[((mh*4 + mm)*4 + c)*512 + lane8];
    if (s == 0) {
      #pragma unroll
      for (int c = 0; c < 4; ++c) {
        n1f[c] = *(const bf16x8*)&N1T[(m8*4 + c)*512 + lane8];
        n2f[c] = *(const bf16x8*)&N2T[(m8*4 + c)*512 + lane8];
      }
    }

    // ---- phase 1: s_p2 = h@W2 ; s_p3 = h@W3 + ce
    // wave w: m-slice m8, node-half nh, t in [0,2)
    {
      floatx4 ce4 = *(const floatx4*)&cev[(g*2 + s)*128 + fme];
      #pragma unroll
      for (int t = 0; t < 2; ++t) {
        const int i = nh*32 + t*16 + xn;
        floatx4 a2 = (floatx4)0.f, a3 = (floatx4)0.f;
        #pragma unroll
        for (int c = 0; c < 4; ++c) {
          bf16x8 bh = *(const bf16x8*)&s_h[i*LDE + c*32 + q*8];
          a2 = MFMA16(w2f[c], bh, a2);
          a3 = MFMA16(w3f[c], bh, a3);
        }
        bf16x4 o2, o3;
        #pragma unroll
        for (int r = 0; r < 4; ++r) { o2[r] = (__bf16)a2[r]; o3[r] = (__bf16)(a3[r] + ce4[r]); }
        *(bf16x4*)&s_p2[i*LDE + fme] = o2;
        *(bf16x4*)&s_p3[i*LDE + fme] = o3;
      }
    }
    __syncthreads();

    // ---- phase 2: ee += leaky(ee@W1 + p2[src] + p3[dst])
    // wave-pair wp owns 32 edges; mh splits m
    {
      bf16x8 be[2][4];
      #pragma unroll
      for (int t = 0; t < 2; ++t) {
        int e = wp*32 + t*16 + xn;
        #pragma unroll
        for (int c = 0; c < 4; ++c)
          be[t][c] = *(const bf16x8*)&s_ee[e*LDE + c*32 + q*8];
      }
      __syncthreads();   // snapshot complete before any pair-member writes
      #pragma unroll
      for (int mm = 0; mm < 4; ++mm) {
        const int m = mh*4 + mm;
        floatx4 acc[2];
        #pragma unroll
        for (int t = 0; t < 2; ++t) acc[t] = (floatx4)0.f;
        #pragma unroll
        for (int c = 0; c < 4; ++c) {
          #pragma unroll
          for (int t = 0; t < 2; ++t) acc[t] = MFMA16(w1f[mm][c], be[t][c], acc[t]);
        }
        const int f0 = m*16 + q*4;
        #pragma unroll
        for (int t = 0; t < 2; ++t) {
          int e = wp*32 + t*16 + xn;
          bf16x4 old = *(const bf16x4*)&s_ee[e*LDE + f0];
          bf16x4 v2  = *(const bf16x4*)&s_p2[mySrc[t]*LDE + f0];
          bf16x4 v3  = *(const bf16x4*)&s_p3[myDst[t]*LDE + f0];
          bf16x4 res;
          #pragma unroll
          for (int r = 0; r < 4; ++r) {
            float vv = acc[t][r] + (float)v2[r] + (float)v3[r];
            res[r] = (__bf16)((float)old[r] + leaky(vv));
          }
          *(bf16x4*)&s_ee[e*LDE + f0] = res;
        }
      }
    }
    __syncthreads();

    if (s == 0) {  // last step's node update is unused -> skip
      // ---- phase 3: agg = segment_sum(ee, dst) -> s_p2 (bf16). 16 thr/node.
      {
        const int node = tid >> 4;
        const int fs = (tid & 15)*8;
        float av[8];
        #pragma unroll
        for (int j = 0; j < 8; ++j) av[j] = 0.f;
        const int b0 = s_off[node], b1 = s_off[node + 1];
        for (int idx = b0; idx < b1; ++idx) {
          int e = s_eid[idx];
          bf16x8 vv = *(const bf16x8*)&s_ee[e*LDE + fs];
          #pragma unroll
          for (int j = 0; j < 8; ++j) av[j] += (float)vv[j];
        }
        bf16x8 o;
        #pragma unroll
        for (int j = 0; j < 8; ++j) o[j] = (__bf16)av[j];
        *(bf16x8*)&s_p2[node*LDE + fs] = o;
      }
      __syncthreads();
      // ---- phase 4: h += leaky(h@Wn1 + agg@Wn2 + cn)
      // wave w: m-slice m8, node-half nh, t in [0,2)
      {
        floatx4 acc4[2];
        #pragma unroll
        for (int t = 0; t < 2; ++t) {
          const int i = nh*32 + t*16 + xn;
          floatx4 a = (floatx4)0.f;
          #pragma unroll
          for (int c = 0; c < 4; ++c) {
            bf16x8 bh = *(const bf16x8*)&s_h[i*LDE + c*32 + q*8];
            a = MFMA16(n1f[c], bh, a);
          }
          #pragma unroll
          for (int c = 0; c < 4; ++c) {
            bf16x8 bg = *(const bf16x8*)&s_p2[i*LDE + c*32 + q*8];
            a = MFMA16(n2f[c], bg, a);
          }
          acc4[t] = a;
        }
        __syncthreads();   // all k-reads of s_h complete before any f-slice write
        floatx4 cn4 = *(const floatx4*)&cnv[(g*2 + s)*128 + fme];
        #pragma unroll
        for (int t = 0; t < 2; ++t) {
          const int i = nh*32 + t*16 + xn;
          bf16x4 old = *(const bf16x4*)&s_h[i*LDE + fme];
          bf16x4 res;
          #pragma unroll
          for (int r = 0; r < 4; ++r)
            res[r] = (__bf16)((float)old[r] + leaky(acc4[t][r] + cn4[r]));
          *(bf16x4*)&s_h[i*LDE + fme] = res;
        }
      }
      __syncthreads();
    }
  }

  // ---- scores: out[g, e, d] = ee[e] . wscore + b  (fp32 output)
  // 4 threads/edge (qq = tid&3 owns features qq*32..+31); in-wave shfl reduce.
  {
    const int e = tid >> 2, qq = tid & 3;
    float acc = 0.f;
    #pragma unroll
    for (int c = 0; c < 4; ++c) {
      bf16x8 vv = *(const bf16x8*)&s_ee[e*LDE + qq*32 + c*8];
      #pragma unroll
      for (int j = 0; j < 8; ++j) acc += (float)vv[j] * wscore[qq*32 + c*8 + j];
    }
    acc += __shfl_xor(acc, 1);
    acc += __shfl_xor(acc, 2);
    if (qq == 0) out[g*16384 + e*64 + d] = acc + bscore[0];
  }
}

extern "C" void kernel_launch(void* const* d_in, const int* in_sizes, int n_in,
                              void* d_out, int out_size, void* d_ws, size_t ws_size,
                              hipStream_t stream) {
  (void)in_sizes; (void)n_in; (void)out_size; (void)ws_size;
  const float* x   = (const float*)d_in[0];
  const float* ea  = (const float*)d_in[1];
  const float* u   = (const float*)d_in[2];
  const float* sp  = (const float*)d_in[3];
  const int*   ei  = (const int*)d_in[4];
  const float* Wne = (const float*)d_in[5];
  const float* bne = (const float*)d_in[6];
  const float* Wee = (const float*)d_in[7];
  const float* bee = (const float*)d_in[8];
  const float* Wge = (const float*)d_in[9];
  const float* bge = (const float*)d_in[10];
  const float* Weu = (const float*)d_in[11];
  const float* beu = (const float*)d_in[12];
  const float* Wnu = (const float*)d_in[13];
  const float* bnu = (const float*)d_in[14];
  const float* Wsc = (const float*)d_in[15];
  const float* bsc = (const float*)d_in[16];
  char* ws = (char*)d_ws;

  hipLaunchKernelGGL(mpn_prep, dim3(44), dim3(256), 0, stream,
                     x, ea, u, ei, Wne, bne, Wee, bee, Wge, bge, Weu, beu, Wnu, bnu, ws);
  hipLaunchKernelGGL(mpn_main, dim3(512), dim3(1024), 0, stream,
                     sp, ei, Wne, Wsc, bsc, (const char*)ws, (float*)d_out);
}

// Round 12
// 154.012 us; speedup vs baseline: 1.1422x; 1.1422x over previous
//
#include <hip/hip_runtime.h>
#include <hip/hip_bf16.h>

// MPNScoreModule: B=8 graphs, N=64 nodes, E=256 edges, L=128, S=2 steps.
// Round 22: fit the 1024-thread main into the 64-VGPR budget the compiler
// insists on (r19/r20/r21: three attribute knobs all ignored, VGPR=64,
// ~98MB scratch = the whole 68us runtime). Change: DELETE the step-start
// weight prefetch (160 VGPRs live across phases -> spill) and load each
// phase's fragments just-in-time:
//  - phase 1: w2f/w3f (32 regs) loaded inside the phase;
//  - phase 2: '#pragma unroll 1' mm-loop, w1c[4] (16 regs) loaded per mm
//    (addresses mm-dependent -> unhoistable); be snapshot stays in regs
//    (32, irreducible: guards the pair-write race);
//  - phase 4: n1f/n2f (32 regs) loaded inside the phase.
// Same fragment load count as before (once/step) -> FETCH back to ~5MB;
// only live ranges change. Per-phase peak ~58-74 regs vs ~224 before.

typedef __attribute__((ext_vector_type(8))) __bf16 bf16x8;
typedef __attribute__((ext_vector_type(4))) __bf16 bf16x4;
typedef __attribute__((ext_vector_type(4))) float  floatx4;

#define MFMA16(a, b, c) __builtin_amdgcn_mfma_f32_16x16x32_bf16((a), (b), (c), 0, 0, 0)

__device__ __forceinline__ float leaky(float x) { return x > 0.f ? x : 0.01f * x; }

// ---- workspace layout (bytes) ----
#define WS_WT     0          // bf16 [10][16384] PACKED weights: [m][(mq*4+c)*64+l][8]
#define WS_XAP    327680     // f32  [8][64][128]  x @ Wne[0:128] + b_node_enc
#define WS_XDP    589824     // f32  [8][64][128]  x @ Wne[128:256]
#define WS_EE0    851968     // bf16 [8][256][128] leaky(edge_attr @ Wee + b)
#define WS_CE     1376256    // f32  [8][2][128]   gg @ W4  + b_edge_upd
#define WS_CN     1384448    // f32  [8][2][128]   gg @ Wn3 + b_node_upd
#define WS_CSROFF 1392640    // int  [8][72]
#define WS_CSREID 1394944    // int  [8][256]
// end ~1.4 MB

#define LDE 140   // padded LDS row stride: 280 B = 70 dw = 6 mod 32 -> conflict-free

// ============================ prep kernel (round 8, unchanged) ============================
__global__ __launch_bounds__(256) void mpn_prep(
    const float* __restrict__ x,     // [8][64][128]
    const float* __restrict__ ea,    // [8][256][128]
    const float* __restrict__ u,     // [8][128]
    const int*   __restrict__ eidx,  // [8][2][256]
    const float* __restrict__ Wne,   // [257][128]
    const float* __restrict__ bne,   // [128]
    const float* __restrict__ Wee,   // [128][128]
    const float* __restrict__ bee,   // [128]
    const float* __restrict__ Wge,   // [128][128]
    const float* __restrict__ bge,   // [128]
    const float* __restrict__ Weu,   // [2][512][128]
    const float* __restrict__ beu,   // [2][128]
    const float* __restrict__ Wnu,   // [2][384][128]
    const float* __restrict__ bnu,   // [2][128]
    char* __restrict__ ws)
{
  __shared__ __align__(16) __bf16 smem[384 * LDE];

  const int b = blockIdx.x, tid = threadIdx.x;
  __bf16* wt  = (__bf16*)(ws + WS_WT);
  float*  xap = (float*)(ws + WS_XAP);
  float*  xdp = (float*)(ws + WS_XDP);
  __bf16* ee0 = (__bf16*)(ws + WS_EE0);
  float*  cev = (float*)(ws + WS_CE);
  float*  cnv = (float*)(ws + WS_CN);
  int* csroff = (int*)(ws + WS_CSROFF);
  int* csreid = (int*)(ws + WS_CSREID);

  if (b < 20) {
    // pack the 10 [128][128] weight blocks into wave-load order:
    // wt[m*16384 + ((mq*4+c)*64 + l)*8 + j] = src[(c*32 + (l>>4)*8 + j)*128 + mq*16 + (l&15)]
    const int m = b >> 1, half = b & 1;
    const int s = m / 5, t = m % 5;
    const float* src = (t < 3) ? (Weu + (size_t)(s*512 + t*128)*128)
                               : (Wnu + (size_t)(s*384 + (t-3)*128)*128);
    for (int it = 0; it < 4; ++it) {
      int p = it*256 + tid;
      int mq = half*4 + (p >> 8);
      int c  = (p >> 6) & 3;
      int l  = p & 63;
      int fr = mq*16 + (l & 15);
      int kb = c*32 + (l >> 4)*8;
      __bf16* dst = &wt[m*16384 + ((mq*4 + c)*64 + l)*8];
      #pragma unroll
      for (int j = 0; j < 8; ++j)
        dst[j] = (__bf16)src[(kb + j)*128 + fr];
    }
  } else if (b < 28) {
    const int g = b - 20;
    __shared__ float gg_sh[128];
    __shared__ int dst_sh[256];
    __shared__ int cnt_sh[64];
    __shared__ int off_sh[65];
    if (tid < 128) {
      float acc = bge[tid];
      for (int k = 0; k < 128; ++k)
        acc += u[g*128 + k] * Wge[k*128 + tid];
      gg_sh[tid] = leaky(acc);
    }
    dst_sh[tid] = eidx[g*512 + 256 + tid];
    __syncthreads();
    {
      const int s = tid >> 7, f = tid & 127;
      float ac = beu[s*128 + f];
      float an = bnu[s*128 + f];
      #pragma unroll 8
      for (int k = 0; k < 128; ++k) {
        float gk = gg_sh[k];
        ac += gk * Weu[(s*512 + 384 + k)*128 + f];
        an += gk * Wnu[(s*384 + 256 + k)*128 + f];
      }
      cev[(g*2 + s)*128 + f] = ac;
      cnv[(g*2 + s)*128 + f] = an;
    }
    if (tid < 64) {
      int c = 0;
      for (int e = 0; e < 256; ++e) c += (dst_sh[e] == tid) ? 1 : 0;
      cnt_sh[tid] = c;
    }
    __syncthreads();
    if (tid == 0) {
      int o = 0;
      for (int n = 0; n < 64; ++n) { off_sh[n] = o; o += cnt_sh[n]; }
      off_sh[64] = o;
    }
    __syncthreads();
    if (tid < 65) csroff[g*72 + tid] = off_sh[tid];
    if (tid < 64) {
      int o = off_sh[tid];
      for (int e = 0; e < 256; ++e)
        if (dst_sh[e] == tid) csreid[g*256 + (o++)] = e;
    }
  } else if (b < 36) {
    // ee0 = leaky(edge_attr @ Wee + bee) via MFMA, one block per graph
    const int g = b - 28;
    __bf16* s_a = smem;
    __bf16* s_w = smem + 256*LDE;
    #pragma unroll
    for (int it = 0; it < 32; ++it) {
      int c = it*256 + tid;
      int row = c >> 5, f4 = (c & 31)*4;
      floatx4 v = *(const floatx4*)&ea[(size_t)(g*256 + row)*128 + f4];
      bf16x4 o;
      #pragma unroll
      for (int r = 0; r < 4; ++r) o[r] = (__bf16)v[r];
      *(bf16x4*)&s_a[row*LDE + f4] = o;
    }
    #pragma unroll 8
    for (int it = 0; it < 64; ++it) {
      int k = it*2 + (tid >> 7), f = tid & 127;
      s_w[f*LDE + k] = (__bf16)Wee[k*128 + f];
    }
    __syncthreads();
    const int w = tid >> 6, l = tid & 63, q = l >> 4, xn = l & 15;
    bf16x8 bea[4][4];
    #pragma unroll
    for (int t = 0; t < 4; ++t) {
      int e = w*64 + t*16 + xn;
      #pragma unroll
      for (int c = 0; c < 4; ++c)
        bea[t][c] = *(const bf16x8*)&s_a[e*LDE + c*32 + q*8];
    }
    #pragma unroll
    for (int m = 0; m < 8; ++m) {
      floatx4 acc[4];
      #pragma unroll
      for (int t = 0; t < 4; ++t) acc[t] = (floatx4)0.f;
      const int fr = m*16 + xn;
      #pragma unroll
      for (int c = 0; c < 4; ++c) {
        bf16x8 aw = *(const bf16x8*)&s_w[fr*LDE + c*32 + q*8];
        #pragma unroll
        for (int t = 0; t < 4; ++t) acc[t] = MFMA16(aw, bea[t][c], acc[t]);
      }
      const int f0 = m*16 + q*4;
      floatx4 b4 = *(const floatx4*)&bee[f0];
      #pragma unroll
      for (int t = 0; t < 4; ++t) {
        int e = w*64 + t*16 + xn;
        bf16x4 o;
        #pragma unroll
        for (int r = 0; r < 4; ++r) o[r] = (__bf16)leaky(acc[t][r] + b4[r]);
        *(bf16x4*)&ee0[(size_t)(g*256 + e)*128 + f0] = o;
      }
    }
  } else {
    // xap = x @ Wne[0:128] + bne ; xdp = x @ Wne[128:256]  via MFMA, per graph
    const int g = b - 36;
    __bf16* s_x  = smem;
    __bf16* s_wa = smem + 64*LDE;
    __bf16* s_wb = smem + 192*LDE;
    #pragma unroll
    for (int it = 0; it < 8; ++it) {
      int c = it*256 + tid;
      int row = c >> 5, f4 = (c & 31)*4;
      floatx4 v = *(const floatx4*)&x[(size_t)(g*64 + row)*128 + f4];
      bf16x4 o;
      #pragma unroll
      for (int r = 0; r < 4; ++r) o[r] = (__bf16)v[r];
      *(bf16x4*)&s_x[row*LDE + f4] = o;
    }
    #pragma unroll 8
    for (int it = 0; it < 64; ++it) {
      int k = it*2 + (tid >> 7), f = tid & 127;
      s_wa[f*LDE + k] = (__bf16)Wne[k*128 + f];
      s_wb[f*LDE + k] = (__bf16)Wne[(128 + k)*128 + f];
    }
    __syncthreads();
    const int w = tid >> 6, l = tid & 63, q = l >> 4, xn = l & 15;
    const int i = w*16 + xn;
    bf16x8 bx[4];
    #pragma unroll
    for (int c = 0; c < 4; ++c)
      bx[c] = *(const bf16x8*)&s_x[i*LDE + c*32 + q*8];
    #pragma unroll
    for (int m = 0; m < 8; ++m) {
      floatx4 aa = (floatx4)0.f, ab = (floatx4)0.f;
      const int fr = m*16 + xn;
      #pragma unroll
      for (int c = 0; c < 4; ++c) {
        bf16x8 aw = *(const bf16x8*)&s_wa[fr*LDE + c*32 + q*8];
        aa = MFMA16(aw, bx[c], aa);
      }
      #pragma unroll
      for (int c = 0; c < 4; ++c) {
        bf16x8 aw = *(const bf16x8*)&s_wb[fr*LDE + c*32 + q*8];
        ab = MFMA16(aw, bx[c], ab);
      }
      const int f0 = m*16 + q*4;
      floatx4 bn4 = *(const floatx4*)&bne[f0];
      floatx4 oa;
      #pragma unroll
      for (int r = 0; r < 4; ++r) oa[r] = aa[r] + bn4[r];
      *(floatx4*)&xap[(size_t)(g*64 + i)*128 + f0] = oa;
      *(floatx4*)&xdp[(size_t)(g*64 + i)*128 + f0] = ab;
    }
  }
}

// ============================ main kernel ============================
// 1024 threads = 16 waves, designed to FIT the 64-VGPR budget:
// no cross-phase weight prefetch; fragments loaded just-in-time per phase
// (phase-2's w1c[4] inside an unroll-1 mm-loop -> unhoistable).
// Phases 1/4: wave w -> (m = w>>1, node-half nh = w&1), t in [0,2).
// Phase 2: 8 wave-pairs x 32 edges, mh = w&1 splits m; be[2][4] snapshot.
// Phase 3: 16 thr/node x 8 features. Scores: 4 thr/edge + shfl_xor.
__global__ __launch_bounds__(1024, 1)
void mpn_main(
    const float* __restrict__ spdist,  // [8][64][64]
    const int*   __restrict__ eidx,    // [8][2][256]
    const float* __restrict__ Wne,     // row 256 = spdist weight
    const float* __restrict__ wscore,  // [128]
    const float* __restrict__ bscore,  // [1]
    const char* __restrict__ ws,
    float* __restrict__ out)           // [8][256][64]  (g*16384 + e*64 + d), fp32
{
  __shared__ __align__(16) __bf16 s_ee[256*LDE];   // edge state
  __shared__ __align__(16) __bf16 s_h [64*LDE];    // node state
  __shared__ __align__(16) __bf16 s_p2[64*LDE];    // h@W2 (reused as agg)
  __shared__ __align__(16) __bf16 s_p3[64*LDE];    // h@W3 + ce
  __shared__ int s_off[65];
  __shared__ int s_eid[256];

  const __bf16* wt  = (const __bf16*)(ws + WS_WT);
  const float*  xap = (const float*)(ws + WS_XAP);
  const float*  xdp = (const float*)(ws + WS_XDP);
  const __bf16* ee0 = (const __bf16*)(ws + WS_EE0);
  const float*  cev = (const float*)(ws + WS_CE);
  const float*  cnv = (const float*)(ws + WS_CN);
  const int* csroff = (const int*)(ws + WS_CSROFF);
  const int* csreid = (const int*)(ws + WS_CSREID);

  const int tid = threadIdx.x;
  const int w = tid >> 6, l = tid & 63;
  const int q = l >> 4, xn = l & 15;
  const int wp = w >> 1;                  // phase-2 wave pair (8 pairs x 32 edges)
  const int mh = w & 1;                   // phase-2 m-half
  const int m8 = w >> 1;                  // phase-1/4 m-slice in [0,8)
  const int nh = w & 1;                   // phase-1/4 node-half
  const int lane8 = l*8;                  // packed-fragment lane offset
  const int fme = m8*16 + q*4;            // phase-1/4 epilogue f-offset
  const int g = blockIdx.x >> 6, d = blockIdx.x & 63;

  if (tid < 65) s_off[tid] = csroff[g*72 + tid];
  if (tid < 256) s_eid[tid] = csreid[g*256 + tid];

  // node encoder: h[i][f] = leaky(xap[i][f] + xdp[d][f] + sp(d,i)*wsp[f])
  {
    const int f = tid & 127, ib = tid >> 7;   // ib in [0,8)
    float xdpv = xdp[(g*64 + d)*128 + f];
    float wspv = Wne[256*128 + f];
    #pragma unroll
    for (int j = 0; j < 8; ++j) {
      int i = ib + 8*j;
      float sp = spdist[(g*64 + d)*64 + i];
      float v = xap[(g*64 + i)*128 + f] + xdpv + sp*wspv;
      s_h[i*LDE + f] = (__bf16)leaky(v);
    }
  }
  // stage ee0 -> LDS (4096 chunks of 16B)
  #pragma unroll
  for (int it = 0; it < 4; ++it) {
    int c = it*1024 + tid;
    int row = c >> 4, col = c & 15;
    *(bf16x8*)&s_ee[row*LDE + col*8] = *(const bf16x8*)&ee0[(g*256 + row)*128 + col*8];
  }

  // phase-2 per-lane src/dst (e = wp*32 + t*16 + xn)
  int mySrc[2], myDst[2];
  #pragma unroll
  for (int t = 0; t < 2; ++t) {
    int e = wp*32 + t*16 + xn;
    mySrc[t] = eidx[g*512 + e];
    myDst[t] = eidx[g*512 + 256 + e];
  }
  __syncthreads();

  for (int s = 0; s < 2; ++s) {
    const __bf16* W1T = wt + (s*5 + 0)*16384;
    const __bf16* W2T = wt + (s*5 + 1)*16384;
    const __bf16* W3T = wt + (s*5 + 2)*16384;
    const __bf16* N1T = wt + (s*5 + 3)*16384;
    const __bf16* N2T = wt + (s*5 + 4)*16384;

    // ---- phase 1: s_p2 = h@W2 ; s_p3 = h@W3 + ce
    // wave w: m-slice m8, node-half nh, t in [0,2).
    // w2f/w3f loaded HERE (live only this phase).
    {
      bf16x8 w2f[4], w3f[4];
      #pragma unroll
      for (int c = 0; c < 4; ++c) {
        w2f[c] = *(const bf16x8*)&W2T[(m8*4 + c)*512 + lane8];
        w3f[c] = *(const bf16x8*)&W3T[(m8*4 + c)*512 + lane8];
      }
      floatx4 ce4 = *(const floatx4*)&cev[(g*2 + s)*128 + fme];
      #pragma unroll
      for (int t = 0; t < 2; ++t) {
        const int i = nh*32 + t*16 + xn;
        floatx4 a2 = (floatx4)0.f, a3 = (floatx4)0.f;
        #pragma unroll
        for (int c = 0; c < 4; ++c) {
          bf16x8 bh = *(const bf16x8*)&s_h[i*LDE + c*32 + q*8];
          a2 = MFMA16(w2f[c], bh, a2);
          a3 = MFMA16(w3f[c], bh, a3);
        }
        bf16x4 o2, o3;
        #pragma unroll
        for (int r = 0; r < 4; ++r) { o2[r] = (__bf16)a2[r]; o3[r] = (__bf16)(a3[r] + ce4[r]); }
        *(bf16x4*)&s_p2[i*LDE + fme] = o2;
        *(bf16x4*)&s_p3[i*LDE + fme] = o3;
      }
    }
    __syncthreads();

    // ---- phase 2: ee += leaky(ee@W1 + p2[src] + p3[dst])
    // wave-pair wp owns 32 edges; mh splits m. be snapshot in regs
    // (guards pair-write race). w1c loaded per mm inside an unroll-1
    // loop (mm-dependent addresses -> compiler cannot hoist).
    {
      bf16x8 be[2][4];
      #pragma unroll
      for (int t = 0; t < 2; ++t) {
        int e = wp*32 + t*16 + xn;
        #pragma unroll
        for (int c = 0; c < 4; ++c)
          be[t][c] = *(const bf16x8*)&s_ee[e*LDE + c*32 + q*8];
      }
      __syncthreads();   // snapshot complete before any pair-member writes
      #pragma unroll 1
      for (int mm = 0; mm < 4; ++mm) {
        const int m = mh*4 + mm;
        bf16x8 w1c[4];
        #pragma unroll
        for (int c = 0; c < 4; ++c)
          w1c[c] = *(const bf16x8*)&W1T[(m*4 + c)*512 + lane8];
        floatx4 acc[2];
        #pragma unroll
        for (int t = 0; t < 2; ++t) acc[t] = (floatx4)0.f;
        #pragma unroll
        for (int c = 0; c < 4; ++c) {
          #pragma unroll
          for (int t = 0; t < 2; ++t) acc[t] = MFMA16(w1c[c], be[t][c], acc[t]);
        }
        const int f0 = m*16 + q*4;
        #pragma unroll
        for (int t = 0; t < 2; ++t) {
          int e = wp*32 + t*16 + xn;
          bf16x4 old = *(const bf16x4*)&s_ee[e*LDE + f0];
          bf16x4 v2  = *(const bf16x4*)&s_p2[mySrc[t]*LDE + f0];
          bf16x4 v3  = *(const bf16x4*)&s_p3[myDst[t]*LDE + f0];
          bf16x4 res;
          #pragma unroll
          for (int r = 0; r < 4; ++r) {
            float vv = acc[t][r] + (float)v2[r] + (float)v3[r];
            res[r] = (__bf16)((float)old[r] + leaky(vv));
          }
          *(bf16x4*)&s_ee[e*LDE + f0] = res;
        }
      }
    }
    __syncthreads();

    if (s == 0) {  // last step's node update is unused -> skip
      // ---- phase 3: agg = segment_sum(ee, dst) -> s_p2 (bf16). 16 thr/node.
      {
        const int node = tid >> 4;
        const int fs = (tid & 15)*8;
        float av[8];
        #pragma unroll
        for (int j = 0; j < 8; ++j) av[j] = 0.f;
        const int b0 = s_off[node], b1 = s_off[node + 1];
        for (int idx = b0; idx < b1; ++idx) {
          int e = s_eid[idx];
          bf16x8 vv = *(const bf16x8*)&s_ee[e*LDE + fs];
          #pragma unroll
          for (int j = 0; j < 8; ++j) av[j] += (float)vv[j];
        }
        bf16x8 o;
        #pragma unroll
        for (int j = 0; j < 8; ++j) o[j] = (__bf16)av[j];
        *(bf16x8*)&s_p2[node*LDE + fs] = o;
      }
      __syncthreads();
      // ---- phase 4: h += leaky(h@Wn1 + agg@Wn2 + cn)
      // n1f/n2f loaded HERE (live only this phase).
      {
        bf16x8 n1f[4], n2f[4];
        #pragma unroll
        for (int c = 0; c < 4; ++c) {
          n1f[c] = *(const bf16x8*)&N1T[(m8*4 + c)*512 + lane8];
          n2f[c] = *(const bf16x8*)&N2T[(m8*4 + c)*512 + lane8];
        }
        floatx4 acc4[2];
        #pragma unroll
        for (int t = 0; t < 2; ++t) {
          const int i = nh*32 + t*16 + xn;
          floatx4 a = (floatx4)0.f;
          #pragma unroll
          for (int c = 0; c < 4; ++c) {
            bf16x8 bh = *(const bf16x8*)&s_h[i*LDE + c*32 + q*8];
            a = MFMA16(n1f[c], bh, a);
          }
          #pragma unroll
          for (int c = 0; c < 4; ++c) {
            bf16x8 bg = *(const bf16x8*)&s_p2[i*LDE + c*32 + q*8];
            a = MFMA16(n2f[c], bg, a);
          }
          acc4[t] = a;
        }
        __syncthreads();   // all k-reads of s_h complete before any f-slice write
        floatx4 cn4 = *(const floatx4*)&cnv[(g*2 + s)*128 + fme];
        #pragma unroll
        for (int t = 0; t < 2; ++t) {
          const int i = nh*32 + t*16 + xn;
          bf16x4 old = *(const bf16x4*)&s_h[i*LDE + fme];
          bf16x4 res;
          #pragma unroll
          for (int r = 0; r < 4; ++r)
            res[r] = (__bf16)((float)old[r] + leaky(acc4[t][r] + cn4[r]));
          *(bf16x4*)&s_h[i*LDE + fme] = res;
        }
      }
      __syncthreads();
    }
  }

  // ---- scores: out[g, e, d] = ee[e] . wscore + b  (fp32 output)
  // 4 threads/edge (qq = tid&3 owns features qq*32..+31); in-wave shfl reduce.
  {
    const int e = tid >> 2, qq = tid & 3;
    float acc = 0.f;
    #pragma unroll
    for (int c = 0; c < 4; ++c) {
      bf16x8 vv = *(const bf16x8*)&s_ee[e*LDE + qq*32 + c*8];
      #pragma unroll
      for (int j = 0; j < 8; ++j) acc += (float)vv[j] * wscore[qq*32 + c*8 + j];
    }
    acc += __shfl_xor(acc, 1);
    acc += __shfl_xor(acc, 2);
    if (qq == 0) out[g*16384 + e*64 + d] = acc + bscore[0];
  }
}

extern "C" void kernel_launch(void* const* d_in, const int* in_sizes, int n_in,
                              void* d_out, int out_size, void* d_ws, size_t ws_size,
                              hipStream_t stream) {
  (void)in_sizes; (void)n_in; (void)out_size; (void)ws_size;
  const float* x   = (const float*)d_in[0];
  const float* ea  = (const float*)d_in[1];
  const float* u   = (const float*)d_in[2];
  const float* sp  = (const float*)d_in[3];
  const int*   ei  = (const int*)d_in[4];
  const float* Wne = (const float*)d_in[5];
  const float* bne = (const float*)d_in[6];
  const float* Wee = (const float*)d_in[7];
  const float* bee = (const float*)d_in[8];
  const float* Wge = (const float*)d_in[9];
  const float* bge = (const float*)d_in[10];
  const float* Weu = (const float*)d_in[11];
  const float* beu = (const float*)d_in[12];
  const float* Wnu = (const float*)d_in[13];
  const float* bnu = (const float*)d_in[14];
  const float* Wsc = (const float*)d_in[15];
  const float* bsc = (const float*)d_in[16];
  char* ws = (char*)d_ws;

  hipLaunchKernelGGL(mpn_prep, dim3(44), dim3(256), 0, stream,
                     x, ea, u, ei, Wne, bne, Wee, bee, Wge, bge, Weu, beu, Wnu, bnu, ws);
  hipLaunchKernelGGL(mpn_main, dim3(512), dim3(1024), 0, stream,
                     sp, ei, Wne, Wsc, bsc, (const char*)ws, (float*)d_out);
}